// Round 1
// baseline (328.959 us; speedup 1.0000x reference)
//
#include <hip/hip_runtime.h>

// StockLSTM R14 = R13 restructured for 2 independent blocks/CU:
//  MT=8, 512 threads (8 waves), grid=512 -> 2 blocks per CU. Breaks the
//  1-block/CU lockstep-barrier wall (VALUBusy 62%, 38% idle): each SIMD now
//  hosts 2 waves from each of 2 blocks with independent barrier cadences.
//  Dual-tile trick: each wave computes 2 row-tiles (j = 8w+q and 8w+4+q)
//  sharing ONE B-fragment whose 16 cols hold the 8 batches twice
//  (b_eff = lane&7). Tile0 cols 0-7 and tile1 cols 8-15 are both real, so
//  the per-lane gate vector is a 4x v_cndmask select -- no lane shuffles,
//  no duplicated transcendentals, LDS reads stay 5/wave. h is stored
//  duplicated at b and b+8 (2 extra ds_write_b16) so reads keep the proven
//  R13 layout. Bias rides as the MFMA C operand (discarded cols tolerate
//  the wrong bias). Cost: 14 MFMA/wave-step (2x inst count, pipe has
//  headroom at 24%), 4-way bank conflict on h reads (non-critical pipe).

#define TT   256
#define II   5
#define HH   64
#define OO   25
#define MT   8
#define NTHR 512
#define XP   520        // x chunk row stride (ushorts): 64*8 + 8 skew
#define HSZ  1024       // h parity block: 64 k * 16 batch-cols shorts (b dup'd)
#define HF   65

typedef __attribute__((ext_vector_type(8))) short  short8;
typedef __attribute__((ext_vector_type(4))) float  floatx4;

#define MFMA(a, b, c) __builtin_amdgcn_mfma_f32_16x16x32_bf16(a, b, c, 0, 0, 0)

__device__ __forceinline__ float frcp(float x) { return __builtin_amdgcn_rcpf(x); }
__device__ __forceinline__ float fexp2(float x) { return __builtin_amdgcn_exp2f(x); }
__device__ __forceinline__ unsigned short bf16_rne(float f) {
    unsigned int u = __builtin_bit_cast(unsigned int, f);
    u += 0x7FFFu + ((u >> 16) & 1u);
    return (unsigned short)(u >> 16);
}
// gates arrive PRE-SCALED: g0,g1,g3 = -log2e*z ; g2 = +2log2e*z
__device__ __forceinline__ float cell_update(const floatx4& g, float& c) {
    const float gi = frcp(1.f + fexp2(g[0]));
    const float gf = frcp(1.f + fexp2(g[1]));
    const float gz = fmaf(-2.f, frcp(1.f + fexp2(g[2])), 1.f);
    const float go = frcp(1.f + fexp2(g[3]));
    c = fmaf(gf, c, gi * gz);
    const float tc = fmaf(-2.f, frcp(1.f + fexp2(c * 2.885390082f)), 1.f);
    return go * tc;
}

__global__ __attribute__((amdgpu_flat_work_group_size(512, 512),
                          amdgpu_waves_per_eu(4, 4)))
void lstm_mfma10(const float* __restrict__ x,
                 const float* __restrict__ Wih0, const float* __restrict__ Whh0,
                 const float* __restrict__ bih0, const float* __restrict__ bhh0,
                 const float* __restrict__ Wih1, const float* __restrict__ Whh1,
                 const float* __restrict__ bih1, const float* __restrict__ bhh1,
                 const float* __restrict__ Wfc,  const float* __restrict__ bfc,
                 float* __restrict__ out)
{
    __shared__ __align__(16) unsigned short xhi[MT * XP];     // 8.3 KB
    __shared__ __align__(16) unsigned short h1hi[2 * HSZ];    // 4 KB
    __shared__ __align__(16) unsigned short h2hi[2 * HSZ];    // 4 KB
    __shared__ __align__(16) float          h2f[MT * HF];

    const int tid   = threadIdx.x;
    const int w     = tid >> 6;          // wave 0..7
    const int lane  = tid & 63;
    const int b8    = lane & 7;          // batch col (8 real, dup'd to 16)
    const int q     = lane >> 4;         // k-slice / C row-quad
    const int sel   = (lane >> 3) & 1;   // which tile this lane's cell comes from
    const bool low  = (sel == 0);
    const int jmine = 8 * w + 4 * sel + q;
    const int hw_off = w * 128 + b8 * 8 + 4 * sel + q;  // shorts; dup at +64
    const int ro8    = (q * 16 + b8) * 8;               // B-frag read offset

    // ---------------- weights (bf16), nonlinearity scale folded in ----------------
    // Per wave: 2 tiles (s=0,1) of 16 gate-rows each.
    short8 A1h[2][2];   // [tile][k-chunk] Whh0
    short8 A2h[2][4];   // [tile][k-chunk] 0,1: Wih1 (h1); 2,3: Whh1 (h2)
    short8 Axwh[2];     // [tile] Wih0: k<II valid, rest exact zero
    {
        const int rr = lane & 15;
        const float sc = ((rr & 3) == 2) ? 2.885390082f : -1.442695041f;
        #pragma unroll
        for (int s = 0; s < 2; ++s) {
            const int g = (rr & 3) * 64 + 8 * w + 4 * s + (rr >> 2);
            #pragma unroll
            for (int c = 0; c < 2; ++c)
                #pragma unroll
                for (int jj = 0; jj < 8; ++jj)
                    A1h[s][c][jj] = (short)bf16_rne(sc * Whh0[g * HH + c * 32 + q * 8 + jj]);
            #pragma unroll
            for (int c = 0; c < 4; ++c)
                #pragma unroll
                for (int jj = 0; jj < 8; ++jj) {
                    const int k = c * 32 + q * 8 + jj;
                    float wv = (k < HH) ? Wih1[g * HH + k] : Whh1[g * HH + (k - HH)];
                    A2h[s][c][jj] = (short)bf16_rne(sc * wv);
                }
            #pragma unroll
            for (int jj = 0; jj < 8; ++jj) {
                const int k = q * 8 + jj;
                Axwh[s][jj] = (k < II) ? (short)bf16_rne(sc * Wih0[g * II + k]) : (short)0;
            }
        }
    }
    // bias as MFMA C-operand: lane carries the bias of ITS merged j; the
    // discarded tile-half gets the wrong bias but is never read.
    floatx4 bias1v, bias2v;
    #pragma unroll
    for (int r = 0; r < 4; ++r) {
        const int g = r * 64 + jmine;
        const float sc = (r == 2) ? 2.885390082f : -1.442695041f;
        bias1v[r] = sc * (bih0[g] + bhh0[g]);
        bias2v[r] = sc * (bih1[g] + bhh1[g]);
    }

    // ---------------- zero LDS ----------------
    for (int i = tid; i < MT * XP / 2; i += NTHR)
        ((unsigned int*)xhi)[i] = 0u;
    for (int i = tid; i < HSZ; i += NTHR) {
        ((unsigned int*)h1hi)[i] = 0u;
        ((unsigned int*)h2hi)[i] = 0u;
    }
    float c1 = 0.f, c2 = 0.f;
    __syncthreads();

    const int blockBase = blockIdx.x * MT;

    auto refill_x = [&](int t0) {
        const int rb = tid >> 6, dt = tid & 63;   // rb 0..7 covers all 8 rows
        const float* src = x + ((size_t)(blockBase + rb) * TT + t0 + dt) * II;
        unsigned short* ph = xhi + rb * XP + dt * 8;
        #pragma unroll
        for (int ii = 0; ii < II; ++ii)
            ph[ii] = bf16_rne(src[ii]);
    };

    // ================= prologue: L1(0) =================
    refill_x(0);
    __syncthreads();
    {
        short8 Bxh = *(const short8*)(xhi + b8 * XP);       // dt = 0
        floatx4 a1t0 = MFMA(Axwh[0], Bxh, bias1v);
        floatx4 a1t1 = MFMA(Axwh[1], Bxh, bias1v);
        floatx4 a1m;
        #pragma unroll
        for (int r = 0; r < 4; ++r) a1m[r] = low ? a1t0[r] : a1t1[r];
        const float h = cell_update(a1m, c1);
        const unsigned short hv = bf16_rne(h);
        h1hi[0 * HSZ + hw_off]      = hv;                   // parity 0, col b
        h1hi[0 * HSZ + hw_off + 64] = hv;                   // dup col b+8
    }
    __syncthreads();

    // x read pointer: STEP(i) reads dt=(i+1)&63; starts at dt=1.
    const unsigned short* xptr = xhi + b8 * XP + 8;

    // ================= merged main loop, unrolled by 2 =================
#define STEP_BODY(WP, RP)                                                     \
    {                                                                         \
        short8 H1h0 = *(const short8*)(h1hi + (WP) * HSZ + ro8);              \
        short8 H1h1 = *(const short8*)(h1hi + (WP) * HSZ + 512 + ro8);        \
        short8 H2h0 = *(const short8*)(h2hi + (RP) * HSZ + ro8);              \
        short8 H2h1 = *(const short8*)(h2hi + (RP) * HSZ + 512 + ro8);        \
        short8 Bxh  = *(const short8*)(xptr);                                 \
        xptr += 8;                                                            \
        floatx4 a2t0 = MFMA(A2h[0][0], H1h0, bias2v);                         \
        floatx4 a2t1 = MFMA(A2h[1][0], H1h0, bias2v);                         \
        a2t0 = MFMA(A2h[0][1], H1h1, a2t0);                                   \
        a2t1 = MFMA(A2h[1][1], H1h1, a2t1);                                   \
        a2t0 = MFMA(A2h[0][2], H2h0, a2t0);                                   \
        a2t1 = MFMA(A2h[1][2], H2h0, a2t1);                                   \
        a2t0 = MFMA(A2h[0][3], H2h1, a2t0);                                   \
        a2t1 = MFMA(A2h[1][3], H2h1, a2t1);                                   \
        floatx4 a1t0 = MFMA(Axwh[0], Bxh, bias1v);                            \
        floatx4 a1t1 = MFMA(Axwh[1], Bxh, bias1v);                            \
        a1t0 = MFMA(A1h[0][0], H1h0, a1t0);                                   \
        a1t1 = MFMA(A1h[1][0], H1h0, a1t1);                                   \
        a1t0 = MFMA(A1h[0][1], H1h1, a1t0);                                   \
        a1t1 = MFMA(A1h[1][1], H1h1, a1t1);                                   \
        floatx4 a2m, a1m;                                                     \
        _Pragma("unroll")                                                     \
        for (int r = 0; r < 4; ++r) a2m[r] = low ? a2t0[r] : a2t1[r];         \
        _Pragma("unroll")                                                     \
        for (int r = 0; r < 4; ++r) a1m[r] = low ? a1t0[r] : a1t1[r];         \
        {                                                                     \
            const float h = cell_update(a2m, c2);                             \
            const unsigned short hv = bf16_rne(h);                            \
            h2hi[(WP) * HSZ + hw_off]      = hv;                              \
            h2hi[(WP) * HSZ + hw_off + 64] = hv;                              \
        }                                                                     \
        {                                                                     \
            const float h = cell_update(a1m, c1);                             \
            const unsigned short hv = bf16_rne(h);                            \
            h1hi[(RP) * HSZ + hw_off]      = hv;                              \
            h1hi[(RP) * HSZ + hw_off + 64] = hv;                              \
        }                                                                     \
        __syncthreads();                                                      \
    }

    for (int i = 0; i < 254; i += 2) {
        STEP_BODY(0, 1)                      // interval i   (even)
        if (((i + 2) & 63) == 0) {           // refill before interval i+1
            refill_x(i + 2);
            xptr = xhi + b8 * XP;            //   next read is dt = 0
            __syncthreads();
        }
        STEP_BODY(1, 0)                      // interval i+1 (odd)
    }
    STEP_BODY(0, 1)                          // interval 254
#undef STEP_BODY

    // ================= epilogue: L2(255) =================
    {
        short8 H1h0 = *(const short8*)(h1hi + 1 * HSZ + ro8);
        short8 H1h1 = *(const short8*)(h1hi + 1 * HSZ + 512 + ro8);
        short8 H2h0 = *(const short8*)(h2hi + 0 * HSZ + ro8);
        short8 H2h1 = *(const short8*)(h2hi + 0 * HSZ + 512 + ro8);
        floatx4 a2t0 = MFMA(A2h[0][0], H1h0, bias2v);
        floatx4 a2t1 = MFMA(A2h[1][0], H1h0, bias2v);
        a2t0 = MFMA(A2h[0][1], H1h1, a2t0);
        a2t1 = MFMA(A2h[1][1], H1h1, a2t1);
        a2t0 = MFMA(A2h[0][2], H2h0, a2t0);
        a2t1 = MFMA(A2h[1][2], H2h0, a2t1);
        a2t0 = MFMA(A2h[0][3], H2h1, a2t0);
        a2t1 = MFMA(A2h[1][3], H2h1, a2t1);
        floatx4 a2m;
        #pragma unroll
        for (int r = 0; r < 4; ++r) a2m[r] = low ? a2t0[r] : a2t1[r];
        const float h = cell_update(a2m, c2);
        h2f[b8 * HF + jmine] = h;
    }
    __syncthreads();

    // ================= FC epilogue =================
    if (tid < MT * OO) {
        const int bb = tid / OO, o = tid - bb * OO;
        float acc = bfc[o];
        const float* wr = Wfc + o * HH;
        const float* hr = h2f + bb * HF;
        #pragma unroll
        for (int j = 0; j < HH; ++j) acc += wr[j] * hr[j];
        out[((size_t)blockIdx.x * MT + bb) * OO + o] = acc;
    }
}

extern "C" void kernel_launch(void* const* d_in, const int* in_sizes, int n_in,
                              void* d_out, int out_size, void* d_ws, size_t ws_size,
                              hipStream_t stream) {
    const float* x    = (const float*)d_in[0];
    const float* Wih0 = (const float*)d_in[1];
    const float* Whh0 = (const float*)d_in[2];
    const float* bih0 = (const float*)d_in[3];
    const float* bhh0 = (const float*)d_in[4];
    const float* Wih1 = (const float*)d_in[5];
    const float* Whh1 = (const float*)d_in[6];
    const float* bih1 = (const float*)d_in[7];
    const float* bhh1 = (const float*)d_in[8];
    const float* Wfc  = (const float*)d_in[9];
    const float* bfc  = (const float*)d_in[10];
    float* out = (float*)d_out;

    dim3 grid(4096 / MT), block(NTHR);
    lstm_mfma10<<<grid, block, 0, stream>>>(x, Wih0, Whh0, bih0, bhh0,
                                            Wih1, Whh1, bih1, bhh1,
                                            Wfc, bfc, out);
}